// Round 5
// baseline (1179.109 us; speedup 1.0000x reference)
//
#include <hip/hip_runtime.h>
#include <hip/hip_bf16.h>
#include <cstdint>
#include <cstddef>

typedef __bf16 bf16_t;
typedef __bf16 bf16x4 __attribute__((ext_vector_type(4)));
typedef __bf16 bf16x8 __attribute__((ext_vector_type(8)));
typedef float  f32x16 __attribute__((ext_vector_type(16)));

#define L_DIM 2048
#define N_DIM 8
#define E_DIM 2048
#define H_DIM 8192
#define T_DIM (L_DIM * N_DIM)   // 16384 tokens

// ---------------------------------------------------------------------------
// fp32 -> bf16 conversion
// ---------------------------------------------------------------------------
__global__ __launch_bounds__(256) void cvt_f32_bf16(const float* __restrict__ in,
                                                    bf16_t* __restrict__ out,
                                                    int n4) {
    int stride = gridDim.x * blockDim.x;
    for (int i = blockIdx.x * blockDim.x + threadIdx.x; i < n4; i += stride) {
        float4 v = *(const float4*)(in + (size_t)i * 4);
        bf16x4 o;
        o[0] = (bf16_t)v.x; o[1] = (bf16_t)v.y;
        o[2] = (bf16_t)v.z; o[3] = (bf16_t)v.w;
        *(bf16x4*)(out + (size_t)i * 4) = o;
    }
}

// ---------------------------------------------------------------------------
// Fast GELU (tanh approximation), branch-free, HW exp2/rcp.
// ---------------------------------------------------------------------------
__device__ __forceinline__ float fast_gelu(float x) {
    float x2 = x * x;
    float w  = x * __builtin_fmaf(0.1029456f, x2, 2.3022618f);
    w = fminf(w, 60.0f);
    float s = __builtin_amdgcn_exp2f(w);          // v_exp_f32
    float r = __builtin_amdgcn_rcpf(s + 1.0f);    // v_rcp_f32
    return x * s * r;
}

// ---------------------------------------------------------------------------
// Persistent 256x256 8-phase GEMM, 32x32x16 MFMA variant.
// C[M,N] = A[M,K] * B[N,K]^T, bf16 in, f32 acc. Grid = 256 blocks.
// 8 waves (2 Mwaves x 4 Nwaves), per-wave output 128x64 = 4 Mfrag x 2 Nfrag
// of 32x32. Phase p computes Mfrag p (rows p*64 + wr*32 .. +31) -> identical
// half-tile consumption order to the verified 16x16 template; sync/vmcnt
// schedule byte-identical. A/B frag: elem(lane, j) = [row|col = lane&31,
// k = (lane>>5)*8 + j]. C/D frag (verified m74/m101): col = lane&31,
// row = (reg&3) + 8*(reg>>2) + 4*(lane>>5).
// LDS swizzle: 16B-slot s -> s ^ (row & 7), on both staging source and reads.
// ---------------------------------------------------------------------------
template <bool GELU_OUT>
__global__ __launch_bounds__(512, 2) void gemm256(const bf16_t* __restrict__ Am,
                                                  const bf16_t* __restrict__ Bm,
                                                  const float* __restrict__ bias,
                                                  void* __restrict__ Cout,
                                                  int N, int K,
                                                  int lgNT, int lgTn, int lgNtile) {
    extern __shared__ char lds[];
    const int NT    = 1 << lgNT;        // K-tiles per output tile (K/64)
    const int ntile = 1 << lgNtile;     // output tiles per block
    const int U     = ntile << lgNT;    // total flat K-iterations

    const int tid  = threadIdx.x;
    const int lane = tid & 63;
    const int wid  = tid >> 6;
    const int wr   = wid >> 2;   // 0..1
    const int wc   = wid & 3;    // 0..3

    // XCD-aware bijective swizzle over the fixed 256-block grid (q = 32)
    const int wgb = (blockIdx.x & 7) * 32 + (blockIdx.x >> 3);

    // staging lane geometry (unchanged from verified template)
    const int srow  = wid * 8 + (lane >> 3);
    const int scol8 = ((lane & 7) ^ (lane >> 3)) * 8;

    auto STAGE = [&](int isB, int half, int slot) {
        const int us  = (slot < U) ? slot : (U - 1);       // clamp tail (dummy)
        const int ti_ = us >> lgNT;
        const int kt_ = us & (NT - 1);
        const int g_  = (wgb << lgNtile) + ti_;
        const size_t base_ = (size_t)(isB ? (g_ & ((1 << lgTn) - 1)) : (g_ >> lgTn)) << 8;
        // parity from UNCLAMPED slot -> dummies land in the non-live buffer
        const unsigned reg_ = (unsigned)(((slot & 1) << 16) | (isB << 15) | (half << 14));
        const bf16_t* s0 = (isB ? Bm : Am)
                         + (base_ + (size_t)(half * 128 + srow)) * (size_t)K
                         + (size_t)((kt_ << 6) + scol8);
        __builtin_amdgcn_global_load_lds(
            (const __attribute__((address_space(1))) void*)s0,
            (__attribute__((address_space(3))) void*)(lds + reg_ + (unsigned)(wid * 1024)),
            16, 0, 0);
        __builtin_amdgcn_global_load_lds(
            (const __attribute__((address_space(1))) void*)(s0 + (size_t)64 * K),
            (__attribute__((address_space(3))) void*)(lds + reg_ + (unsigned)((8 + wid) * 1024)),
            16, 0, 0);
    };

    // 32x32 fragment LDS reads. Element k = ks*16 + (lane>>5)*8 -> 16B-slot
    // s = 2*ks + (lane>>5); physical slot = s ^ (row&7).
    const int lrow = lane & 31;
    const int lhi  = lane >> 5;
    auto ldsA = [&](unsigned bufo, int mf, int ks) -> bf16x8 {
        const int row  = mf * 64 + wr * 32 + lrow;
        const int slot = (2 * ks + lhi) ^ (row & 7);
        return *(const bf16x8*)(lds + bufo + row * 128 + slot * 16);
    };
    auto ldsB = [&](unsigned bufo, int nf, int ks) -> bf16x8 {
        const int row  = wc * 64 + nf * 32 + lrow;
        const int slot = (2 * ks + lhi) ^ (row & 7);
        return *(const bf16x8*)(lds + bufo + 32768 + row * 128 + slot * 16);
    };

    f32x16 acc[4][2] = {};

    // Prologue: flat slots 0 (full) + 1 (partial: B0,B1,A0)
    STAGE(1, 0, 0); STAGE(1, 1, 0); STAGE(0, 0, 0); STAGE(0, 1, 0);
    STAGE(1, 0, 1); STAGE(1, 1, 1); STAGE(0, 0, 1);
    asm volatile("s_waitcnt vmcnt(6)" ::: "memory");   // slot 0 landed
    __builtin_amdgcn_s_barrier();

    for (int ti = 0; ti < ntile; ++ti) {
        const int g0 = (wgb << lgNtile) + ti;
        const size_t rowBase = (size_t)(g0 >> lgTn) << 8;
        const size_t colBase = (size_t)(g0 & ((1 << lgTn) - 1)) << 8;
        // bias preload (2 scalars/lane); consumed at this tile's epilogue.
        const float bv0 = bias[colBase + (size_t)(wc * 64 + lrow)];
        const float bv1 = bias[colBase + (size_t)(wc * 64 + 32 + lrow)];

        for (int t = 0; t < NT; ++t) {
            const int u = (ti << lgNT) + t;
            const unsigned cur = (unsigned)(t & 1) * 65536u;   // == (u&1), NT even
            bf16x8 bf[2][4];
            bf16x8 af[4];

            // ---- phase 0: all B (8 reads) + A mf0 (4 reads); stage A1(u+1) ----
#pragma unroll
            for (int nf = 0; nf < 2; ++nf)
#pragma unroll
                for (int ks = 0; ks < 4; ++ks)
                    bf[nf][ks] = ldsB(cur, nf, ks);
#pragma unroll
            for (int ks = 0; ks < 4; ++ks)
                af[ks] = ldsA(cur, 0, ks);
            STAGE(0, 1, u + 1);
            asm volatile("s_waitcnt lgkmcnt(8)" ::: "memory");
            __builtin_amdgcn_s_barrier();
            asm volatile("s_waitcnt lgkmcnt(0)" ::: "memory");
            __builtin_amdgcn_s_setprio(1);
#pragma unroll
            for (int ks = 0; ks < 4; ++ks)
#pragma unroll
                for (int nf = 0; nf < 2; ++nf)
                    acc[0][nf] = __builtin_amdgcn_mfma_f32_32x32x16_bf16(
                        af[ks], bf[nf][ks], acc[0][nf], 0, 0, 0);
            __builtin_amdgcn_s_setprio(0);
            __builtin_amdgcn_s_barrier();

            // ---- phases 1..3: A mf=ph; stage B0/B1/A0 of (u+2) ----
#pragma unroll
            for (int ph = 1; ph < 4; ++ph) {
#pragma unroll
                for (int ks = 0; ks < 4; ++ks)
                    af[ks] = ldsA(cur, ph, ks);
                if (ph == 1)      STAGE(1, 0, u + 2);
                else if (ph == 2) STAGE(1, 1, u + 2);
                else {            STAGE(0, 0, u + 2);
                                  asm volatile("s_waitcnt vmcnt(6)" ::: "memory"); }
                __builtin_amdgcn_s_barrier();
                asm volatile("s_waitcnt lgkmcnt(0)" ::: "memory");
                __builtin_amdgcn_s_setprio(1);
#pragma unroll
                for (int ks = 0; ks < 4; ++ks)
#pragma unroll
                    for (int nf = 0; nf < 2; ++nf)
                        acc[ph][nf] = __builtin_amdgcn_mfma_f32_32x32x16_bf16(
                            af[ks], bf[nf][ks], acc[ph][nf], 0, 0, 0);
                __builtin_amdgcn_s_setprio(0);
                __builtin_amdgcn_s_barrier();
            }
        }

        // ---- per-tile epilogue (reg-only; no VM loads, stores only) ----
        const size_t colb0 = colBase + (size_t)(wc * 64 + lrow);
#pragma unroll
        for (int mf = 0; mf < 4; ++mf) {
            const size_t r0 = rowBase + (size_t)(mf * 64 + wr * 32 + 4 * lhi);
#pragma unroll
            for (int nf = 0; nf < 2; ++nf) {
                const size_t cb = colb0 + (size_t)(nf * 32);
                const float bv = nf ? bv1 : bv0;
#pragma unroll
                for (int r = 0; r < 16; ++r) {
                    const size_t rr = r0 + (size_t)((r & 3) + 8 * (r >> 2));
                    float v = acc[mf][nf][r] + bv;
                    if constexpr (GELU_OUT) {
                        ((bf16_t*)Cout)[rr * (size_t)N + cb] = (bf16_t)fast_gelu(v);
                    } else {
                        ((float*)Cout)[rr * (size_t)N + cb] = v;
                    }
                }
                acc[mf][nf] = f32x16{};
            }
        }
    }
    asm volatile("s_waitcnt vmcnt(0)" ::: "memory");   // drain tail dummy loads
}

// ---------------------------------------------------------------------------
extern "C" void kernel_launch(void* const* d_in, const int* in_sizes, int n_in,
                              void* d_out, int out_size, void* d_ws, size_t ws_size,
                              hipStream_t stream) {
    const float* x  = (const float*)d_in[0];  // [16384, 2048]
    const float* p1 = (const float*)d_in[1];  // [8192, 2048]
    const float* b1 = (const float*)d_in[2];  // [8192]
    const float* p2 = (const float*)d_in[3];  // [2048, 8192]
    const float* b2 = (const float*)d_in[4];  // [2048]
    // d_in[5] = gate_w, unused (routing is identity on the output)
    float* out = (float*)d_out;

    char* ws = (char*)d_ws;
    bf16_t* xb  = (bf16_t*)(ws);                          // 64 MB
    bf16_t* p1b = (bf16_t*)(ws + ((size_t)64 << 20));     // 32 MB
    bf16_t* p2b = (bf16_t*)(ws + ((size_t)96 << 20));     // 32 MB
    bf16_t* h   = (bf16_t*)(ws + ((size_t)128 << 20));    // 256 MB

    (void)hipFuncSetAttribute((const void*)gemm256<true>,
                              hipFuncAttributeMaxDynamicSharedMemorySize, 131072);
    (void)hipFuncSetAttribute((const void*)gemm256<false>,
                              hipFuncAttributeMaxDynamicSharedMemorySize, 131072);

    cvt_f32_bf16<<<2048, 256, 0, stream>>>(x,  xb,  (T_DIM * E_DIM) / 4);
    cvt_f32_bf16<<<1024, 256, 0, stream>>>(p1, p1b, (H_DIM * E_DIM) / 4);
    cvt_f32_bf16<<<1024, 256, 0, stream>>>(p2, p2b, (E_DIM * H_DIM) / 4);

    // GEMM1: [T,E] x [H,E]^T -> h[T,H]. 2048 tiles = 256 blocks x 8 tiles.
    // NT = 2048/64 = 32 (lg 5), nTn = 8192/256 = 32 (lg 5), ntile = 8 (lg 3).
    gemm256<true><<<256, 512, 131072, stream>>>(
        xb, p1b, b1, (void*)h, H_DIM, E_DIM, 5, 5, 3);

    // GEMM2: [T,H] x [E,H]^T -> out[T,E]. 512 tiles = 256 blocks x 2 tiles.
    // NT = 8192/64 = 128 (lg 7), nTn = 2048/256 = 8 (lg 3), ntile = 2 (lg 1).
    gemm256<false><<<256, 512, 131072, stream>>>(
        h, p2b, b2, (void*)out, E_DIM, H_DIM, 7, 3, 1);
}

// Round 6
// 1054.812 us; speedup vs baseline: 1.1178x; 1.1178x over previous
//
#include <hip/hip_runtime.h>
#include <hip/hip_bf16.h>
#include <cstdint>
#include <cstddef>

typedef __bf16 bf16_t;
typedef __bf16 bf16x4 __attribute__((ext_vector_type(4)));
typedef __bf16 bf16x8 __attribute__((ext_vector_type(8)));
typedef float  f32x4  __attribute__((ext_vector_type(4)));

#define L_DIM 2048
#define N_DIM 8
#define E_DIM 2048
#define H_DIM 8192
#define T_DIM (L_DIM * N_DIM)   // 16384 tokens

// ---------------------------------------------------------------------------
// fp32 -> bf16 conversion
// ---------------------------------------------------------------------------
__global__ __launch_bounds__(256) void cvt_f32_bf16(const float* __restrict__ in,
                                                    bf16_t* __restrict__ out,
                                                    int n4) {
    int stride = gridDim.x * blockDim.x;
    for (int i = blockIdx.x * blockDim.x + threadIdx.x; i < n4; i += stride) {
        float4 v = *(const float4*)(in + (size_t)i * 4);
        bf16x4 o;
        o[0] = (bf16_t)v.x; o[1] = (bf16_t)v.y;
        o[2] = (bf16_t)v.z; o[3] = (bf16_t)v.w;
        *(bf16x4*)(out + (size_t)i * 4) = o;
    }
}

// ---------------------------------------------------------------------------
// Fast GELU (tanh approximation), branch-free, HW exp2/rcp.
// ---------------------------------------------------------------------------
__device__ __forceinline__ float fast_gelu(float x) {
    float x2 = x * x;
    float w  = x * __builtin_fmaf(0.1029456f, x2, 2.3022618f);
    w = fminf(w, 60.0f);
    float s = __builtin_amdgcn_exp2f(w);          // v_exp_f32
    float r = __builtin_amdgcn_rcpf(s + 1.0f);    // v_rcp_f32
    return x * s * r;
}

// ---------------------------------------------------------------------------
// Persistent 256x256 8-phase GEMM (R4 structure, 16x16x32 MFMA), with ALL
// geometry as compile-time template parameters so STAGE/ds_read address
// arithmetic constant-folds (R4 was VALU-bound on runtime-parameter math:
// MfmaUtil 45 / VALUBusy 34 at 2 waves/SIMD => ceiling = max(MFMA,VALU)).
// Schedule, staging, swizzle, fragment layout byte-identical to R4.
// ---------------------------------------------------------------------------
template <bool GELU_OUT, int LG_NT, int LG_TN, int LG_NTILE, int KDIM, int NDIM>
__global__ __launch_bounds__(512, 2) void gemm256(const bf16_t* __restrict__ Am,
                                                  const bf16_t* __restrict__ Bm,
                                                  const float* __restrict__ bias,
                                                  void* __restrict__ Cout) {
    extern __shared__ char lds[];
    constexpr int NT    = 1 << LG_NT;      // K-tiles per output tile (KDIM/64)
    constexpr int ntile = 1 << LG_NTILE;   // output tiles per block
    constexpr int U     = ntile << LG_NT;  // total flat K-iterations

    const int tid  = threadIdx.x;
    const int lane = tid & 63;
    const int wid  = tid >> 6;
    const int wr   = wid >> 2;   // 0..1
    const int wc   = wid & 3;    // 0..3

    // XCD-aware bijective swizzle over the fixed 256-block grid (q = 32)
    const int wgb = (blockIdx.x & 7) * 32 + (blockIdx.x >> 3);

    // staging lane geometry: row_in_half = wid*8 + (lane>>3), phys slot = lane&7,
    // pre-swizzled logical col slot = (lane&7) ^ (row&7)  [row&7 == lane>>3]
    const int srow  = wid * 8 + (lane >> 3);
    const int scol8 = ((lane & 7) ^ (lane >> 3)) * 8;

    auto STAGE = [&](int isB, int half, int slot) {
        const int us  = (slot < U) ? slot : (U - 1);       // clamp tail (dummy)
        const int ti_ = us >> LG_NT;
        const int kt_ = us & (NT - 1);
        const int g_  = (wgb << LG_NTILE) + ti_;
        const size_t base_ = (size_t)(isB ? (g_ & ((1 << LG_TN) - 1)) : (g_ >> LG_TN)) << 8;
        // parity from UNCLAMPED slot -> dummies land in the non-live buffer
        const unsigned reg_ = (unsigned)(((slot & 1) << 16) | (isB << 15) | (half << 14));
        const bf16_t* s0 = (isB ? Bm : Am)
                         + (base_ + (size_t)(half * 128 + srow)) * (size_t)KDIM
                         + (size_t)((kt_ << 6) + scol8);
        __builtin_amdgcn_global_load_lds(
            (const __attribute__((address_space(1))) void*)s0,
            (__attribute__((address_space(3))) void*)(lds + reg_ + (unsigned)(wid * 1024)),
            16, 0, 0);
        __builtin_amdgcn_global_load_lds(
            (const __attribute__((address_space(1))) void*)(s0 + (size_t)64 * KDIM),
            (__attribute__((address_space(3))) void*)(lds + reg_ + (unsigned)((8 + wid) * 1024)),
            16, 0, 0);
    };

    // M-frag m of wave wr -> tile row (m>>1)*64 + wr*32 + (m&1)*16
    auto ldsA = [&](unsigned bufo, int m, int kk) -> bf16x8 {
        const int row  = (m >> 1) * 64 + wr * 32 + (m & 1) * 16 + (lane & 15);
        const int slot = ((kk << 2) + (lane >> 4)) ^ (lane & 7);
        return *(const bf16x8*)(lds + bufo + row * 128 + slot * 16);
    };
    auto ldsB = [&](unsigned bufo, int n, int kk) -> bf16x8 {
        const int row  = wc * 64 + n * 16 + (lane & 15);
        const int slot = ((kk << 2) + (lane >> 4)) ^ (lane & 7);
        return *(const bf16x8*)(lds + bufo + 32768 + row * 128 + slot * 16);
    };

    f32x4 acc[8][4] = {};

    // Prologue: flat slots 0 (full) + 1 (partial: B0,B1,A0)
    STAGE(1, 0, 0); STAGE(1, 1, 0); STAGE(0, 0, 0); STAGE(0, 1, 0);
    STAGE(1, 0, 1); STAGE(1, 1, 1); STAGE(0, 0, 1);
    asm volatile("s_waitcnt vmcnt(6)" ::: "memory");   // slot 0 landed
    __builtin_amdgcn_s_barrier();

    for (int ti = 0; ti < ntile; ++ti) {
        for (int t = 0; t < NT; ++t) {
            const int u = (ti << LG_NT) + t;
            const unsigned cur = (unsigned)(t & 1) * 65536u;   // == (u&1), NT even
            bf16x8 bf[4][2];
            bf16x8 af[2][2];

            // ---- phase 0: all B (8 reads) + A m=0,1 (4 reads); stage A1(u+1) ----
#pragma unroll
            for (int n = 0; n < 4; ++n)
#pragma unroll
                for (int kk = 0; kk < 2; ++kk)
                    bf[n][kk] = ldsB(cur, n, kk);
#pragma unroll
            for (int mm = 0; mm < 2; ++mm)
#pragma unroll
                for (int kk = 0; kk < 2; ++kk)
                    af[mm][kk] = ldsA(cur, mm, kk);
            STAGE(0, 1, u + 1);
            asm volatile("s_waitcnt lgkmcnt(8)" ::: "memory");
            __builtin_amdgcn_s_barrier();
            asm volatile("s_waitcnt lgkmcnt(0)" ::: "memory");
            __builtin_amdgcn_s_setprio(1);
#pragma unroll
            for (int mm = 0; mm < 2; ++mm)
#pragma unroll
                for (int n = 0; n < 4; ++n)
#pragma unroll
                    for (int kk = 0; kk < 2; ++kk)
                        acc[mm][n] = __builtin_amdgcn_mfma_f32_16x16x32_bf16(
                            af[mm][kk], bf[n][kk], acc[mm][n], 0, 0, 0);
            __builtin_amdgcn_s_setprio(0);
            __builtin_amdgcn_s_barrier();

            // ---- phases 1..3: A m=2p,2p+1; stage B0/B1/A0 of (u+2) ----
#pragma unroll
            for (int ph = 1; ph < 4; ++ph) {
#pragma unroll
                for (int mm = 0; mm < 2; ++mm)
#pragma unroll
                    for (int kk = 0; kk < 2; ++kk)
                        af[mm][kk] = ldsA(cur, ph * 2 + mm, kk);
                if (ph == 1)      STAGE(1, 0, u + 2);
                else if (ph == 2) STAGE(1, 1, u + 2);
                else {            STAGE(0, 0, u + 2);
                                  asm volatile("s_waitcnt vmcnt(6)" ::: "memory"); }
                __builtin_amdgcn_s_barrier();
                asm volatile("s_waitcnt lgkmcnt(0)" ::: "memory");
                __builtin_amdgcn_s_setprio(1);
#pragma unroll
                for (int mm = 0; mm < 2; ++mm)
#pragma unroll
                    for (int n = 0; n < 4; ++n)
#pragma unroll
                        for (int kk = 0; kk < 2; ++kk)
                            acc[ph * 2 + mm][n] = __builtin_amdgcn_mfma_f32_16x16x32_bf16(
                                af[mm][kk], bf[n][kk], acc[ph * 2 + mm][n], 0, 0, 0);
                __builtin_amdgcn_s_setprio(0);
                __builtin_amdgcn_s_barrier();
            }
        }

        // ---- per-tile epilogue (reg-only, no LDS; no extra barrier needed) ----
        const int g = (wgb << LG_NTILE) + ti;
        const size_t rowBase = (size_t)(g >> LG_TN) << 8;
        const size_t colBase = (size_t)(g & ((1 << LG_TN) - 1)) << 8;
        const int orow = (lane >> 4) * 4;
        const int ocol = lane & 15;
#pragma unroll
        for (int m = 0; m < 8; ++m) {
            const size_t rb = rowBase + (size_t)((m >> 1) * 64 + wr * 32 + (m & 1) * 16 + orow);
#pragma unroll
            for (int n = 0; n < 4; ++n) {
                const size_t col = colBase + (size_t)(wc * 64 + n * 16 + ocol);
                const float bv = bias[col];
#pragma unroll
                for (int j = 0; j < 4; ++j) {
                    float v = acc[m][n][j] + bv;
                    if constexpr (GELU_OUT) {
                        ((bf16_t*)Cout)[(rb + j) * (size_t)NDIM + col] = (bf16_t)fast_gelu(v);
                    } else {
                        ((float*)Cout)[(rb + j) * (size_t)NDIM + col] = v;
                    }
                }
                acc[m][n] = (f32x4){0.f, 0.f, 0.f, 0.f};
            }
        }
    }
    asm volatile("s_waitcnt vmcnt(0)" ::: "memory");   // drain tail dummy loads
}

// ---------------------------------------------------------------------------
extern "C" void kernel_launch(void* const* d_in, const int* in_sizes, int n_in,
                              void* d_out, int out_size, void* d_ws, size_t ws_size,
                              hipStream_t stream) {
    const float* x  = (const float*)d_in[0];  // [16384, 2048]
    const float* p1 = (const float*)d_in[1];  // [8192, 2048]
    const float* b1 = (const float*)d_in[2];  // [8192]
    const float* p2 = (const float*)d_in[3];  // [2048, 8192]
    const float* b2 = (const float*)d_in[4];  // [2048]
    // d_in[5] = gate_w, unused (routing is identity on the output)
    float* out = (float*)d_out;

    char* ws = (char*)d_ws;
    bf16_t* xb  = (bf16_t*)(ws);                          // 64 MB
    bf16_t* p1b = (bf16_t*)(ws + ((size_t)64 << 20));     // 32 MB
    bf16_t* p2b = (bf16_t*)(ws + ((size_t)96 << 20));     // 32 MB
    bf16_t* h   = (bf16_t*)(ws + ((size_t)128 << 20));    // 256 MB

    // GEMM1: [T,E] x [H,E]^T -> h.  2048 tiles = 256 blocks x 8 tiles.
    // NT = 2048/64 = 32 (lg 5), nTn = 8192/256 = 32 (lg 5), ntile = 8 (lg 3).
    auto g1 = gemm256<true, 5, 5, 3, E_DIM, H_DIM>;
    // GEMM2: [T,H] x [E,H]^T -> out. 512 tiles = 256 blocks x 2 tiles.
    // NT = 8192/64 = 128 (lg 7), nTn = 2048/256 = 8 (lg 3), ntile = 2 (lg 1).
    auto g2 = gemm256<false, 7, 3, 1, H_DIM, E_DIM>;

    (void)hipFuncSetAttribute((const void*)g1,
                              hipFuncAttributeMaxDynamicSharedMemorySize, 131072);
    (void)hipFuncSetAttribute((const void*)g2,
                              hipFuncAttributeMaxDynamicSharedMemorySize, 131072);

    cvt_f32_bf16<<<2048, 256, 0, stream>>>(x,  xb,  (T_DIM * E_DIM) / 4);
    cvt_f32_bf16<<<1024, 256, 0, stream>>>(p1, p1b, (H_DIM * E_DIM) / 4);
    cvt_f32_bf16<<<1024, 256, 0, stream>>>(p2, p2b, (E_DIM * H_DIM) / 4);

    g1<<<256, 512, 131072, stream>>>(xb, p1b, b1, (void*)h);
    g2<<<256, 512, 131072, stream>>>(h, p2b, b2, (void*)out);
}